// Round 1
// baseline (340.987 us; speedup 1.0000x reference)
//
#include <hip/hip_runtime.h>
#include <math.h>

// GATConvQ inference: xw = x@W; per-node score halves ai/aj; dst-CSR counting
// sort; one wave per dst node does segment softmax + weighted aggregation.

#define NEG_SLOPE 0.2f

// ---------------- GEMM: xw[N,128] = x[N,128] @ W[128,128] (fp32) -----------
__global__ __launch_bounds__(256) void gemm_xw_kernel(
    const float* __restrict__ x, const float* __restrict__ w,
    float* __restrict__ xw, int n)
{
    __shared__ float wl[16 * 128];   // W k-chunk [16][128]
    __shared__ float xs[16][65];     // x tile transposed [k][row], +1 pad
    const int t = threadIdx.x;
    const int row0 = blockIdx.x * 64;
    const int tc = t & 31, tr = t >> 5;   // thread cols (x4), thread rows (x8)
    const int r = t >> 2, kq = t & 3;     // x-tile load mapping
    const bool rok = (row0 + r) < n;
    const float4* xrow = (const float4*)(x + (size_t)(row0 + r) * 128);
    const float4* w4 = (const float4*)w;

    float acc[8][4];
#pragma unroll
    for (int i = 0; i < 8; i++)
#pragma unroll
        for (int j = 0; j < 4; j++) acc[i][j] = 0.f;

    for (int k0 = 0; k0 < 128; k0 += 16) {
        float4 xv = make_float4(0.f, 0.f, 0.f, 0.f);
        if (rok) xv = xrow[(k0 >> 2) + kq];
        float4 wv0 = w4[((k0 * 128) >> 2) + t];
        float4 wv1 = w4[((k0 * 128) >> 2) + t + 256];
        __syncthreads();   // previous iteration's LDS reads complete
        xs[kq * 4 + 0][r] = xv.x;
        xs[kq * 4 + 1][r] = xv.y;
        xs[kq * 4 + 2][r] = xv.z;
        xs[kq * 4 + 3][r] = xv.w;
        ((float4*)wl)[t] = wv0;
        ((float4*)wl)[t + 256] = wv1;
        __syncthreads();
#pragma unroll
        for (int kk = 0; kk < 16; kk++) {
            float4 wvv = *(const float4*)&wl[kk * 128 + tc * 4];
            float xr[8];
#pragma unroll
            for (int i = 0; i < 8; i++) xr[i] = xs[kk][tr * 8 + i];
#pragma unroll
            for (int i = 0; i < 8; i++) {
                acc[i][0] += xr[i] * wvv.x;
                acc[i][1] += xr[i] * wvv.y;
                acc[i][2] += xr[i] * wvv.z;
                acc[i][3] += xr[i] * wvv.w;
            }
        }
    }
#pragma unroll
    for (int i = 0; i < 8; i++) {
        int grow = row0 + tr * 8 + i;
        if (grow < n) {
            float4 o = make_float4(acc[i][0], acc[i][1], acc[i][2], acc[i][3]);
            ((float4*)(xw + (size_t)grow * 128))[tc] = o;
        }
    }
}

// ------------- per-node score halves: ai = xw.att[:,:16], aj = .att[:,16:] --
__global__ __launch_bounds__(256) void aiaj_kernel(
    const float* __restrict__ xw, const float* __restrict__ att,
    float* __restrict__ ai, float* __restrict__ aj, int n8)
{
    int t = blockIdx.x * 256 + threadIdx.x;
    if (t >= n8) return;
    int h = t & 7;
    const float4* xp = (const float4*)(xw + (size_t)t * 16);  // t = node*8+h -> node*128+h*16
    const float4* a0 = (const float4*)(att + h * 32);
    const float4* a1 = (const float4*)(att + h * 32 + 16);
    float s0 = 0.f, s1 = 0.f;
#pragma unroll
    for (int q = 0; q < 4; q++) {
        float4 xv = xp[q]; float4 av = a0[q]; float4 bv = a1[q];
        s0 += xv.x * av.x + xv.y * av.y + xv.z * av.z + xv.w * av.w;
        s1 += xv.x * bv.x + xv.y * bv.y + xv.z * bv.z + xv.w * bv.w;
    }
    ai[t] = s0; aj[t] = s1;
}

// ---------------- CSR build: histogram -> scan -> scatter -------------------
__global__ void hist_kernel(const int* __restrict__ dstp,
                            int* __restrict__ counts, int e)
{
    int i = blockIdx.x * 256 + threadIdx.x;
    if (i < e) atomicAdd(&counts[dstp[i]], 1);
}

__global__ __launch_bounds__(256) void scan1_kernel(
    const int* __restrict__ counts, int* __restrict__ rowptr,
    int* __restrict__ blk, int n)
{
    __shared__ int wsum[4];
    const int t = threadIdx.x;
    const int lane = t & 63, w = t >> 6;
    const int base = blockIdx.x * 1024 + t * 4;
    int v[4];
#pragma unroll
    for (int i = 0; i < 4; i++) {
        int idx = base + i;
        v[i] = (idx < n) ? counts[idx] : 0;
    }
    int tsum = v[0] + v[1] + v[2] + v[3];
    int xv = tsum;
#pragma unroll
    for (int off = 1; off < 64; off <<= 1) {
        int y = __shfl_up(xv, off);
        if (lane >= off) xv += y;
    }
    if (lane == 63) wsum[w] = xv;
    __syncthreads();
    int woff = 0;
    for (int i = 0; i < w; i++) woff += wsum[i];
    int run = woff + xv - tsum;   // exclusive prefix for this thread's 4 elems
#pragma unroll
    for (int i = 0; i < 4; i++) {
        int idx = base + i;
        if (idx < n) rowptr[idx] = run;
        run += v[i];
    }
    if (t == 255) blk[blockIdx.x] = woff + xv;  // block total
}

// nb <= 128 (N=100000 -> nb=98)
__global__ __launch_bounds__(128) void scan2_kernel(int* __restrict__ blk, int nb)
{
    __shared__ int w0tot;
    const int t = threadIdx.x;
    const int lane = t & 63, w = t >> 6;
    int v = (t < nb) ? blk[t] : 0;
    int xv = v;
#pragma unroll
    for (int off = 1; off < 64; off <<= 1) {
        int y = __shfl_up(xv, off);
        if (lane >= off) xv += y;
    }
    if (w == 0 && lane == 63) w0tot = xv;
    __syncthreads();
    if (w == 1) xv += w0tot;
    if (t < nb) blk[t] = xv - v;  // exclusive
}

__global__ void scan3_kernel(int* __restrict__ rowptr, const int* __restrict__ blk,
                             int n, int e)
{
    int i = blockIdx.x * 256 + threadIdx.x;
    if (i < n) rowptr[i] += blk[i >> 10];
    if (i == 0) rowptr[n] = e;
}

__global__ void scatter_kernel(const int* __restrict__ srcp, const int* __restrict__ dstp,
                               const int* __restrict__ rowptr, int* __restrict__ cursor,
                               int* __restrict__ ssrc, int e)
{
    int i = blockIdx.x * 256 + threadIdx.x;
    if (i >= e) return;
    int d = dstp[i];
    int pos = rowptr[d] + atomicAdd(&cursor[d], 1);
    ssrc[pos] = srcp[i];
}

// ---------------- one wave per dst node: softmax + aggregate ----------------
__global__ __launch_bounds__(256) void aggregate_kernel(
    const float* __restrict__ xw, const float* __restrict__ ai,
    const float* __restrict__ aj, const int* __restrict__ rowptr,
    const int* __restrict__ ssrc, const float* __restrict__ bias,
    float* __restrict__ out, int n)
{
    const int wid = (blockIdx.x * blockDim.x + threadIdx.x) >> 6;  // node id
    const int lane = threadIdx.x & 63;
    if (wid >= n) return;
    const int start = rowptr[wid];
    const int end = rowptr[wid + 1];
    const int deg = end - start;
    const int h = lane & 7;
    const float a_i = ai[wid * 8 + h];

    // pass 1: per-head max (lanes map to (edge, head), h = lane&7)
    float m = -1e30f;
    for (int eo = lane >> 3; eo < deg; eo += 8) {
        int s = ssrc[start + eo];
        float a = a_i + aj[s * 8 + h];
        a = (a >= 0.f) ? a : NEG_SLOPE * a;
        m = fmaxf(m, a);
    }
    m = fmaxf(m, __shfl_xor(m, 8));
    m = fmaxf(m, __shfl_xor(m, 16));
    m = fmaxf(m, __shfl_xor(m, 32));

    // pass 2: per-head exp-sum
    float ssum = 0.f;
    for (int eo = lane >> 3; eo < deg; eo += 8) {
        int s = ssrc[start + eo];
        float a = a_i + aj[s * 8 + h];
        a = (a >= 0.f) ? a : NEG_SLOPE * a;
        ssum += __expf(a - m);
    }
    ssum += __shfl_xor(ssum, 8);
    ssum += __shfl_xor(ssum, 16);
    ssum += __shfl_xor(ssum, 32);
    const float inv = 1.f / ssum;

    // pass 3: lanes map to channels; ch0 = lane, ch1 = lane+64
    const int h0 = lane >> 4;        // head of ch0 (0..3)
    const int h1 = 4 + (lane >> 4);  // head of ch1 (4..7)
    float acc0 = 0.f, acc1 = 0.f;
    for (int e = start; e < end; e++) {
        int s = ssrc[e];
        // every lane computes the weight for ITS head h = lane&7
        float a = a_i + aj[s * 8 + h];
        a = (a >= 0.f) ? a : NEG_SLOPE * a;
        float wv = __expf(a - m) * inv;
        float w0 = __shfl(wv, h0);   // lane h0 holds head h0's weight
        float w1 = __shfl(wv, h1);
        const float* xr = xw + (size_t)s * 128;
        acc0 += w0 * xr[lane];
        acc1 += w1 * xr[64 + lane];
    }
    out[(size_t)wid * 128 + lane] = acc0 + bias[lane];
    out[(size_t)wid * 128 + 64 + lane] = acc1 + bias[64 + lane];
}

extern "C" void kernel_launch(void* const* d_in, const int* in_sizes, int n_in,
                              void* d_out, int out_size, void* d_ws, size_t ws_size,
                              hipStream_t stream)
{
    const float* x    = (const float*)d_in[0];
    const int*   ei   = (const int*)d_in[1];   // [2, E] int32
    const float* w    = (const float*)d_in[3];
    const float* att  = (const float*)d_in[4];
    const float* bias = (const float*)d_in[5];
    const int N = in_sizes[0] / 128;
    const int E = in_sizes[1] / 2;
    const int* srcp = ei;
    const int* dstp = ei + E;

    // workspace layout (all 16B-aligned by construction)
    float* xw     = (float*)d_ws;                    // N*128
    float* ai     = xw + (size_t)N * 128;            // N*8
    float* aj     = ai + (size_t)N * 8;              // N*8
    int*   counts = (int*)(aj + (size_t)N * 8);      // N
    int*   cursor = counts + N;                      // N
    int*   rowptr = cursor + N;                      // N+1
    int*   blk    = rowptr + (N + 1);                // <=128 (+pad to 256)
    int*   ssrc   = blk + 256;                       // E

    hipMemsetAsync(counts, 0, (size_t)2 * N * sizeof(int), stream);  // counts+cursor

    gemm_xw_kernel<<<(N + 63) / 64, 256, 0, stream>>>(x, w, xw, N);
    aiaj_kernel<<<(N * 8 + 255) / 256, 256, 0, stream>>>(xw, att, ai, aj, N * 8);
    hist_kernel<<<(E + 255) / 256, 256, 0, stream>>>(dstp, counts, E);
    int nb = (N + 1023) / 1024;   // 98 <= 128
    scan1_kernel<<<nb, 256, 0, stream>>>(counts, rowptr, blk, N);
    scan2_kernel<<<1, 128, 0, stream>>>(blk, nb);
    scan3_kernel<<<(N + 255) / 256, 256, 0, stream>>>(rowptr, blk, N, E);
    scatter_kernel<<<(E + 255) / 256, 256, 0, stream>>>(srcp, dstp, rowptr, cursor, ssrc, E);
    aggregate_kernel<<<(N * 64 + 255) / 256, 256, 0, stream>>>(
        xw, ai, aj, rowptr, ssrc, bias, (float*)d_out, N);
}